// Round 3
// baseline (1555.147 us; speedup 1.0000x reference)
//
#include <hip/hip_runtime.h>

typedef unsigned short u16;
typedef unsigned int   u32;

// ---- problem constants ----
// B=4 L=6 X=Y=8 -> 256 sites, W=49 window, D=256, h=8, dh=32
#define SCALE_Q 0.17677669529663687f

__device__ __forceinline__ float bf2f(u16 v){ return __uint_as_float(((u32)v)<<16); }
__device__ __forceinline__ u16 f2bf(float f){
  u32 u = __float_as_uint(f);
  u32 r = u + 0x7FFFu + ((u>>16)&1u);   // round-to-nearest-even
  return (u16)(r>>16);
}
__device__ __forceinline__ void unpack2(u32 v, float& a, float& b){
  a = __uint_as_float(v<<16);
  b = __uint_as_float(v & 0xFFFF0000u);
}
__device__ __forceinline__ u32 pack2(float a, float b){
  return (u32)f2bf(a) | ((u32)f2bf(b)<<16);
}

// diagnostic fill (fp32): encodes which runtime assumption failed
__global__ void flag_fill(float* out, int n, float v){
  int i = blockIdx.x*256 + threadIdx.x;
  if (i < n) out[i] = v;
}

// ---------------------------------------------------------------------------
// K0: fuse relation matrices into projection weights (all fp32 inputs).
// Wf[rel][d][n], n<256: kw cols  = sum_q Wk[ml][h*32+q][d] * Ratt[rel][h][p][q]
//                n>=256: vmsg    = sum_p Wv[ml][h*32+p][d] * Rmsg[rel][h][p][q]
// ---------------------------------------------------------------------------
__global__ __launch_bounds__(512) void fuse_w(
    const float* __restrict__ Wk, const float* __restrict__ Wv,
    const float* __restrict__ Ratt, const float* __restrict__ Rmsg,
    float* __restrict__ Wf)
{
  const int rel = blockIdx.x;      // 0..3
  const int d   = blockIdx.y;      // 0..255
  const int n   = threadIdx.x;     // 0..511
  const int ml  = rel & 1;
  float acc = 0.f;
  if (n < 256) {
    const int h = n >> 5, p = n & 31;
    const float* wcol = Wk + (size_t)ml*65536 + (size_t)(h*32)*256 + d;
    const float* rrow = Ratt + ((size_t)(rel*8 + h)*32 + p)*32;
    #pragma unroll
    for (int q = 0; q < 32; ++q) acc += wcol[q*256] * rrow[q];
  } else {
    const int n2 = n - 256, h = n2 >> 5, qq = n2 & 31;
    const float* wcol = Wv + (size_t)ml*65536 + (size_t)(h*32)*256 + d;
    const float* rcol = Rmsg + ((size_t)(rel*8 + h)*32)*32 + qq;
    #pragma unroll
    for (int p2 = 0; p2 < 32; ++p2) acc += wcol[p2*256] * rcol[p2*32];
  }
  Wf[((size_t)rel*256 + d)*512 + n] = acc;
}

__global__ __launch_bounds__(512) void fuse_b(
    const float* __restrict__ bk, const float* __restrict__ bv,
    const float* __restrict__ Ratt, const float* __restrict__ Rmsg,
    float* __restrict__ bff)
{
  const int rel = blockIdx.x, n = threadIdx.x, ml = rel & 1;
  float acc = 0.f;
  if (n < 256) {
    const int h = n >> 5, p = n & 31;
    const float* rrow = Ratt + ((size_t)(rel*8 + h)*32 + p)*32;
    #pragma unroll
    for (int q = 0; q < 32; ++q) acc += bk[ml*256 + h*32 + q] * rrow[q];
  } else {
    const int n2 = n - 256, h = n2 >> 5, qq = n2 & 31;
    const float* rcol = Rmsg + ((size_t)(rel*8 + h)*32)*32 + qq;
    #pragma unroll
    for (int p2 = 0; p2 < 32; ++p2) acc += bv[ml*256 + h*32 + p2] * rcol[p2*32];
  }
  bff[rel*512 + n] = acc;
}

// ---------------------------------------------------------------------------
// K1: fused kw / v_msg projection GEMM for ONE batch b.
// A = x (fp32) rows (l,xy,ef) x 256, B = Wf[rel] fp32 256x512.
// Output bf16: kw/vm [xy][h][l][ef][p]  (per-b buffers).
// ---------------------------------------------------------------------------
__global__ __launch_bounds__(256) void gemm_kwv(
    const float* __restrict__ x, const int* __restrict__ mode,
    const float* __restrict__ Wf, const float* __restrict__ bff,
    u16* __restrict__ kw, u16* __restrict__ vm, int b)
{
  __shared__ float As[16][68];
  __shared__ float Bs[16][68];
  const int nbase = blockIdx.x * 64;         // 0..448
  const int rowT  = blockIdx.y;              // 0..293
  const int l = rowT / 49, tile = rowT % 49;
  const int bl = b*6 + l;
  const int rel = mode[b*6]*2 + mode[b*6 + l];
  const float* Abase = x + ((size_t)bl*3136 + (size_t)tile*64)*256;
  const float* Bbase = Wf + (size_t)rel*131072 + nbase;
  const int tid = threadIdx.x;
  const int tx = tid & 15, ty = tid >> 4;
  const int arow = tid >> 2, acol = (tid & 3)*4;
  const int brow = tid >> 4, bcol = (tid & 15)*4;
  float acc[4][4] = {};
  for (int k0 = 0; k0 < 256; k0 += 16) {
    float4 ar = *(const float4*)(Abase + (size_t)arow*256 + k0 + acol);
    float4 br = *(const float4*)(Bbase + (size_t)(k0 + brow)*512 + bcol);
    __syncthreads();
    As[acol+0][arow]=ar.x; As[acol+1][arow]=ar.y; As[acol+2][arow]=ar.z; As[acol+3][arow]=ar.w;
    *(float4*)&Bs[brow][bcol] = br;
    __syncthreads();
    #pragma unroll
    for (int kk = 0; kk < 16; ++kk){
      float4 a4 = *(const float4*)&As[kk][ty*4];
      float4 b4 = *(const float4*)&Bs[kk][tx*4];
      float ar_[4] = {a4.x,a4.y,a4.z,a4.w};
      float br_[4] = {b4.x,b4.y,b4.z,b4.w};
      #pragma unroll
      for (int i = 0; i < 4; ++i)
        #pragma unroll
        for (int j = 0; j < 4; ++j) acc[i][j] += ar_[i]*br_[j];
    }
  }
  const int colBase = nbase + tx*4;
  const bool isK = colBase < 256;
  const int n = colBase & 255;
  const int h = n >> 5, p = n & 31;
  u16* dbuf = isK ? kw : vm;
  float bias[4];
  #pragma unroll
  for (int j = 0; j < 4; ++j) bias[j] = bff[rel*512 + colBase + j];
  #pragma unroll
  for (int i = 0; i < 4; ++i){
    int r = tile*64 + ty*4 + i;           // 0..3135 within (b,l)
    int xy = r / 49, ef = r - xy*49;
    size_t dst = (((size_t)(xy*8 + h)*6 + l)*49 + ef)*32 + p;   // per-b buffer
    ushort4 pk;
    pk.x = f2bf(acc[i][0] + bias[0]);
    pk.y = f2bf(acc[i][1] + bias[1]);
    pk.z = f2bf(acc[i][2] + bias[2]);
    pk.w = f2bf(acc[i][3] + bias[3]);
    *(ushort4*)(dbuf + dst) = pk;
  }
}

// ---------------------------------------------------------------------------
// K2: q projection (l=0 only). B = Wq[m0] fp32 [e][d] -> transposed tile load.
// ---------------------------------------------------------------------------
__global__ __launch_bounds__(256) void gemm_q(
    const float* __restrict__ x, const int* __restrict__ mode,
    const float* __restrict__ Wq, const float* __restrict__ bq,
    u16* __restrict__ qbuf)
{
  __shared__ float As[16][68];
  __shared__ float Bs[16][68];
  const int nbase = blockIdx.x * 64;      // 0..192
  const int rowT  = blockIdx.y;           // 0..195
  const int b = rowT / 49, tile = rowT % 49;
  const int m0 = mode[b*6];
  const float* Abase = x + ((size_t)b*6*3136 + (size_t)tile*64)*256;
  const float* Wbase = Wq + (size_t)m0*65536;
  const int tid = threadIdx.x;
  const int tx = tid & 15, ty = tid >> 4;
  const int arow = tid >> 2, acol = (tid & 3)*4;
  const int bn = tid >> 2,  bk4 = (tid & 3)*4;
  float acc[4][4] = {};
  for (int k0 = 0; k0 < 256; k0 += 16) {
    float4 ar = *(const float4*)(Abase + (size_t)arow*256 + k0 + acol);
    float4 br = *(const float4*)(Wbase + (size_t)(nbase + bn)*256 + k0 + bk4);
    __syncthreads();
    As[acol+0][arow]=ar.x; As[acol+1][arow]=ar.y; As[acol+2][arow]=ar.z; As[acol+3][arow]=ar.w;
    Bs[bk4+0][bn]=br.x; Bs[bk4+1][bn]=br.y; Bs[bk4+2][bn]=br.z; Bs[bk4+3][bn]=br.w;
    __syncthreads();
    #pragma unroll
    for (int kk = 0; kk < 16; ++kk){
      float4 a4 = *(const float4*)&As[kk][ty*4];
      float4 b4 = *(const float4*)&Bs[kk][tx*4];
      float ar_[4] = {a4.x,a4.y,a4.z,a4.w};
      float br_[4] = {b4.x,b4.y,b4.z,b4.w};
      #pragma unroll
      for (int i = 0; i < 4; ++i)
        #pragma unroll
        for (int j = 0; j < 4; ++j) acc[i][j] += ar_[i]*br_[j];
    }
  }
  const int colBase = nbase + tx*4;
  const int h = colBase >> 5, p = colBase & 31;
  float bias[4];
  #pragma unroll
  for (int j = 0; j < 4; ++j) bias[j] = bq[m0*256 + colBase + j];
  #pragma unroll
  for (int i = 0; i < 4; ++i){
    int r = tile*64 + ty*4 + i;
    int xy = r / 49, ef = r - xy*49;
    size_t dst = (((size_t)(b*64 + xy)*8 + h)*49 + ef)*32 + p;
    ushort4 pk;
    pk.x = f2bf((acc[i][0]+bias[0])*SCALE_Q);
    pk.y = f2bf((acc[i][1]+bias[1])*SCALE_Q);
    pk.z = f2bf((acc[i][2]+bias[2])*SCALE_Q);
    pk.w = f2bf((acc[i][3]+bias[3])*SCALE_Q);
    *(ushort4*)(qbuf + dst) = pk;
  }
}

// ---------------------------------------------------------------------------
// K3: attention for ONE batch b. One block per (xy,head). 49 q x 294 keys.
// q/kw/vm are bf16 intermediates; pos_table fp32.
// LDS = 57624 + 3328 + 3328 + 676 = 64956 B
// ---------------------------------------------------------------------------
__global__ __launch_bounds__(256) void attn_kernel(
    const u16* __restrict__ qbuf, const u16* __restrict__ kw,
    const u16* __restrict__ vm,   const float* __restrict__ post,
    u16* __restrict__ aout, int b)
{
  __shared__ float sims[49*294];     // [qi][z*49+ke]
  __shared__ u32 qs2[16*52];         // [pp][qi]
  __shared__ u32 ks2[16*52];         // sim: [pp][ke]; PV: flat [ef*16+pp]
  __shared__ float poss[169];
  const int blk = blockIdx.x;              // xy*8+h (local to b)
  const int h = blk & 7, xy = blk >> 3;
  const int bxy = b*64 + xy;
  const int tid = threadIdx.x;
  const u32* qsrc = (const u32*)(qbuf + (size_t)(bxy*8 + h)*1568);
  const u16* kwb  = kw + (size_t)blk*9408;
  const u16* vmb  = vm + (size_t)blk*9408;

  for (int i = tid; i < 784; i += 256) qs2[(i&15)*52 + (i>>4)] = qsrc[i];
  for (int i = tid; i < 169; i += 256) poss[i] = post[i*8 + h];
  __syncthreads();

  const int qt = tid >> 4, kt = tid & 15;   // 16x16 thread grid
  const int qbase = min(qt*4, 48);          // clamped: keep uint4 loads in-bounds
  const int kbase = min(kt*4, 48);
  float biasv[4][4];
  #pragma unroll
  for (int i = 0; i < 4; ++i){
    int qi = min(qbase + i, 48); int qa = qi/7, qb = qi - qa*7;
    #pragma unroll
    for (int j = 0; j < 4; ++j){
      int ke = min(kbase + j, 48); int ka = ke/7, kb2 = ke - ka*7;
      biasv[i][j] = poss[(qa - ka + 6)*13 + (qb - kb2 + 6)];
    }
  }

  // ---- sim = q . kw + bias ----
  for (int z = 0; z < 6; ++z){
    __syncthreads();
    const u32* ksrc = (const u32*)(kwb + (size_t)z*1568);
    for (int i = tid; i < 784; i += 256) ks2[(i&15)*52 + (i>>4)] = ksrc[i];
    __syncthreads();
    float acc[4][4] = {};
    #pragma unroll
    for (int kkp = 0; kkp < 16; ++kkp){
      uint4 a4 = *(const uint4*)&qs2[kkp*52 + qbase];
      uint4 b4 = *(const uint4*)&ks2[kkp*52 + kbase];
      float ql[4], qh[4], kl[4], kh[4];
      unpack2(a4.x, ql[0], qh[0]); unpack2(a4.y, ql[1], qh[1]);
      unpack2(a4.z, ql[2], qh[2]); unpack2(a4.w, ql[3], qh[3]);
      unpack2(b4.x, kl[0], kh[0]); unpack2(b4.y, kl[1], kh[1]);
      unpack2(b4.z, kl[2], kh[2]); unpack2(b4.w, kl[3], kh[3]);
      #pragma unroll
      for (int i = 0; i < 4; ++i)
        #pragma unroll
        for (int j = 0; j < 4; ++j)
          acc[i][j] += ql[i]*kl[j] + qh[i]*kh[j];
    }
    #pragma unroll
    for (int i = 0; i < 4; ++i){
      int qi = qt*4 + i;
      #pragma unroll
      for (int j = 0; j < 4; ++j){
        int ke = kt*4 + j;
        if (qi < 49 && ke < 49) sims[qi*294 + z*49 + ke] = acc[i][j] + biasv[i][j];
      }
    }
  }
  __syncthreads();

  // ---- softmax over 294 keys, one thread per query row ----
  if (tid < 49){
    float* row = &sims[tid*294];
    float m = -1e30f;
    for (int j = 0; j < 294; ++j) m = fmaxf(m, row[j]);
    float s = 0.f;
    for (int j = 0; j < 294; ++j){ float e = __expf(row[j]-m); row[j] = e; s += e; }
    float inv = 1.f/s;
    for (int j = 0; j < 294; ++j) row[j] *= inv;
  }

  // ---- out = attn @ v_msg :  4(q) x 2(p) per thread ----
  const int pt = tid & 15, qt2 = tid >> 4;
  float accx[4] = {0,0,0,0}, accy[4] = {0,0,0,0};
  for (int z = 0; z < 6; ++z){
    __syncthreads();
    const u32* vsrc = (const u32*)(vmb + (size_t)z*1568);
    for (int i = tid; i < 784; i += 256) ks2[i] = vsrc[i];   // flat [ef*16+pp]
    __syncthreads();
    for (int ef = 0; ef < 49; ++ef){
      float v0, v1; unpack2(ks2[ef*16 + pt], v0, v1);
      #pragma unroll
      for (int i = 0; i < 4; ++i){
        int qi = min(qt2*4 + i, 48);
        float w = sims[qi*294 + z*49 + ef];
        accx[i] += w*v0; accy[i] += w*v1;
      }
    }
  }
  u32* outp = (u32*)(aout + (size_t)bxy*12544 + h*32);
  #pragma unroll
  for (int i = 0; i < 4; ++i){
    int qi = qt2*4 + i;
    if (qi < 49) outp[qi*128 + pt] = pack2(accx[i], accy[i]);
  }
}

// ---------------------------------------------------------------------------
// K4: final projection. A = attn out (bf16), B = Wa[m0] fp32 [e][d], bias ba.
// Output fp32 to d_out.
// ---------------------------------------------------------------------------
__global__ __launch_bounds__(256) void gemm_out(
    const u16* __restrict__ aout, const int* __restrict__ mode,
    const float* __restrict__ Wa, const float* __restrict__ ba,
    float* __restrict__ outp)
{
  __shared__ float As[16][68];
  __shared__ float Bs[16][68];
  const int nbase = blockIdx.x * 64;
  const int rowT  = blockIdx.y;           // 0..195
  const int b = rowT / 49, tile = rowT % 49;
  const int m0 = mode[b*6];
  const u16* Abase = aout + ((size_t)b*3136 + (size_t)tile*64)*256;
  const float* Wbase = Wa + (size_t)m0*65536;
  const int tid = threadIdx.x;
  const int tx = tid & 15, ty = tid >> 4;
  const int arow = tid >> 2, acol = (tid & 3)*4;
  const int bn = tid >> 2,  bk4 = (tid & 3)*4;
  float acc[4][4] = {};
  for (int k0 = 0; k0 < 256; k0 += 16) {
    uint2  ar = *(const uint2*)(Abase + (size_t)arow*256 + k0 + acol);
    float4 br = *(const float4*)(Wbase + (size_t)(nbase + bn)*256 + k0 + bk4);
    __syncthreads();
    { float a0,a1,a2,a3; unpack2(ar.x,a0,a1); unpack2(ar.y,a2,a3);
      As[acol+0][arow]=a0; As[acol+1][arow]=a1; As[acol+2][arow]=a2; As[acol+3][arow]=a3; }
    Bs[bk4+0][bn]=br.x; Bs[bk4+1][bn]=br.y; Bs[bk4+2][bn]=br.z; Bs[bk4+3][bn]=br.w;
    __syncthreads();
    #pragma unroll
    for (int kk = 0; kk < 16; ++kk){
      float4 a4 = *(const float4*)&As[kk][ty*4];
      float4 b4 = *(const float4*)&Bs[kk][tx*4];
      float ar_[4] = {a4.x,a4.y,a4.z,a4.w};
      float br_[4] = {b4.x,b4.y,b4.z,b4.w};
      #pragma unroll
      for (int i = 0; i < 4; ++i)
        #pragma unroll
        for (int j = 0; j < 4; ++j) acc[i][j] += ar_[i]*br_[j];
    }
  }
  const int colBase = nbase + tx*4;
  float bias[4];
  #pragma unroll
  for (int j = 0; j < 4; ++j) bias[j] = ba[m0*256 + colBase + j];
  #pragma unroll
  for (int i = 0; i < 4; ++i){
    int rowg = b*3136 + tile*64 + ty*4 + i;
    float4 o;
    o.x = acc[i][0] + bias[0];
    o.y = acc[i][1] + bias[1];
    o.z = acc[i][2] + bias[2];
    o.w = acc[i][3] + bias[3];
    *(float4*)(outp + (size_t)rowg*256 + colBase) = o;
  }
}

// ---------------------------------------------------------------------------
extern "C" void kernel_launch(void* const* d_in, const int* in_sizes, int n_in,
                              void* d_out, int out_size, void* d_ws, size_t ws_size,
                              hipStream_t stream)
{
  float* outp = (float*)d_out;
  const int FLAG_GRID = (out_size + 255)/256;

  // ---- runtime diagnostics (constant across calls -> graph-safe) ----
  if (n_in != 13) { flag_fill<<<FLAG_GRID,256,0,stream>>>(outp, out_size, 2000.f); return; }
  if (in_sizes[0] != 4*6*64*49*256) { flag_fill<<<FLAG_GRID,256,0,stream>>>(outp, out_size, 3000.f); return; }
  if (in_sizes[1] != 24) { flag_fill<<<FLAG_GRID,256,0,stream>>>(outp, out_size, 4000.f); return; }

  const size_t SZ_WF   = (size_t)4*256*512*sizeof(float);   //  2 MB
  const size_t SZ_BFF  = (size_t)4*512*sizeof(float);       //  8 KB
  const size_t SZ_Q    = (size_t)12544*256*2;               //  6.4 MB
  const size_t SZ_KW   = (size_t)64*8*6*49*32*2;            //  9.63 MB (per-b)
  const size_t SZ_AOUT = (size_t)12544*256*2;               //  6.4 MB
  const size_t NEEDED  = SZ_WF + SZ_BFF + SZ_Q + 2*SZ_KW + SZ_AOUT;  // ~34.2 MB
  if (ws_size < NEEDED) { flag_fill<<<FLAG_GRID,256,0,stream>>>(outp, out_size, 1000.f); return; }

  const float* x    = (const float*)d_in[0];
  const int*   mode = (const int*)d_in[1];
  const float* Wq   = (const float*)d_in[2];
  const float* bq   = (const float*)d_in[3];
  const float* Wk   = (const float*)d_in[4];
  const float* bk   = (const float*)d_in[5];
  const float* Wv   = (const float*)d_in[6];
  const float* bv   = (const float*)d_in[7];
  const float* Wa   = (const float*)d_in[8];
  const float* ba   = (const float*)d_in[9];
  const float* Ratt = (const float*)d_in[10];
  const float* Rmsg = (const float*)d_in[11];
  const float* post = (const float*)d_in[12];

  char* w = (char*)d_ws;
  float* Wf   = (float*)w;  w += SZ_WF;
  float* bff  = (float*)w;  w += SZ_BFF;
  u16* qbuf   = (u16*)w;    w += SZ_Q;
  u16* kwbuf  = (u16*)w;    w += SZ_KW;
  u16* vmbuf  = (u16*)w;    w += SZ_KW;
  u16* aout   = (u16*)w;    w += SZ_AOUT;

  fuse_w<<<dim3(4,256), 512, 0, stream>>>(Wk, Wv, Ratt, Rmsg, Wf);
  fuse_b<<<4, 512, 0, stream>>>(bk, bv, Ratt, Rmsg, bff);
  gemm_q<<<dim3(4,196), 256, 0, stream>>>(x, mode, Wq, bq, qbuf);
  for (int b = 0; b < 4; ++b) {
    gemm_kwv<<<dim3(8,294), 256, 0, stream>>>(x, mode, Wf, bff, kwbuf, vmbuf, b);
    attn_kernel<<<512, 256, 0, stream>>>(qbuf, kwbuf, vmbuf, post, aout, b);
  }
  gemm_out<<<dim3(4,196), 256, 0, stream>>>(aout, mode, Wa, ba, outp);
}

// Round 4
// 760.981 us; speedup vs baseline: 2.0436x; 2.0436x over previous
//
#include <hip/hip_runtime.h>

typedef unsigned short u16;
typedef unsigned int   u32;

// ---- problem constants ----
// B=4 L=6 X=Y=8 -> 256 sites, W=49 window, D=256, h=8, dh=32
#define SCALE_Q 0.17677669529663687f

__device__ __forceinline__ float bf2f(u16 v){ return __uint_as_float(((u32)v)<<16); }
__device__ __forceinline__ u16 f2bf(float f){
  u32 u = __float_as_uint(f);
  u32 r = u + 0x7FFFu + ((u>>16)&1u);   // round-to-nearest-even
  return (u16)(r>>16);
}
__device__ __forceinline__ void unpack2(u32 v, float& a, float& b){
  a = __uint_as_float(v<<16);
  b = __uint_as_float(v & 0xFFFF0000u);
}
__device__ __forceinline__ u32 pack2(float a, float b){
  return (u32)f2bf(a) | ((u32)f2bf(b)<<16);
}

// diagnostic fill (fp32): encodes which runtime assumption failed
__global__ void flag_fill(float* out, int n, float v){
  int i = blockIdx.x*256 + threadIdx.x;
  if (i < n) out[i] = v;
}

// ---------------------------------------------------------------------------
// K0: fuse relation matrices into projection weights (all fp32 inputs).
// Wf[rel][d][n], n<256: kw cols  = sum_q Wk[ml][h*32+q][d] * Ratt[rel][h][p][q]
//                n>=256: vmsg    = sum_p Wv[ml][h*32+p][d] * Rmsg[rel][h][p][q]
// ---------------------------------------------------------------------------
__global__ __launch_bounds__(512) void fuse_w(
    const float* __restrict__ Wk, const float* __restrict__ Wv,
    const float* __restrict__ Ratt, const float* __restrict__ Rmsg,
    float* __restrict__ Wf)
{
  const int rel = blockIdx.x;      // 0..3
  const int d   = blockIdx.y;      // 0..255
  const int n   = threadIdx.x;     // 0..511
  const int ml  = rel & 1;
  float acc = 0.f;
  if (n < 256) {
    const int h = n >> 5, p = n & 31;
    const float* wcol = Wk + (size_t)ml*65536 + (size_t)(h*32)*256 + d;
    const float* rrow = Ratt + ((size_t)(rel*8 + h)*32 + p)*32;
    #pragma unroll
    for (int q = 0; q < 32; ++q) acc += wcol[q*256] * rrow[q];
  } else {
    const int n2 = n - 256, h = n2 >> 5, qq = n2 & 31;
    const float* wcol = Wv + (size_t)ml*65536 + (size_t)(h*32)*256 + d;
    const float* rcol = Rmsg + ((size_t)(rel*8 + h)*32)*32 + qq;
    #pragma unroll
    for (int p2 = 0; p2 < 32; ++p2) acc += wcol[p2*256] * rcol[p2*32];
  }
  Wf[((size_t)rel*256 + d)*512 + n] = acc;
}

__global__ __launch_bounds__(512) void fuse_b(
    const float* __restrict__ bk, const float* __restrict__ bv,
    const float* __restrict__ Ratt, const float* __restrict__ Rmsg,
    float* __restrict__ bff)
{
  const int rel = blockIdx.x, n = threadIdx.x, ml = rel & 1;
  float acc = 0.f;
  if (n < 256) {
    const int h = n >> 5, p = n & 31;
    const float* rrow = Ratt + ((size_t)(rel*8 + h)*32 + p)*32;
    #pragma unroll
    for (int q = 0; q < 32; ++q) acc += bk[ml*256 + h*32 + q] * rrow[q];
  } else {
    const int n2 = n - 256, h = n2 >> 5, qq = n2 & 31;
    const float* rcol = Rmsg + ((size_t)(rel*8 + h)*32)*32 + qq;
    #pragma unroll
    for (int p2 = 0; p2 < 32; ++p2) acc += bv[ml*256 + h*32 + p2] * rcol[p2*32];
  }
  bff[rel*512 + n] = acc;
}

// ---------------------------------------------------------------------------
// K1: fused kw / v_msg projection GEMM for a CHUNK of nb batches [b0, b0+nb).
// A = x (fp32) rows (bloc,l,xy,ef) x 256, B = Wf[rel] fp32 256x512.
// Output bf16: kw/vm [bloc][xy][h][l][ef][p]  (chunk-local buffers).
// ---------------------------------------------------------------------------
__global__ __launch_bounds__(256) void gemm_kwv(
    const float* __restrict__ x, const int* __restrict__ mode,
    const float* __restrict__ Wf, const float* __restrict__ bff,
    u16* __restrict__ kw, u16* __restrict__ vm, int b0)
{
  __shared__ float As[16][68];
  __shared__ float Bs[16][68];
  const int nbase = blockIdx.x * 64;         // 0..448
  const int rowT  = blockIdx.y;              // 0..nb*294-1
  const int bloc = rowT / 294;
  const int rem  = rowT % 294;
  const int l = rem / 49, tile = rem % 49;
  const int b = b0 + bloc;
  const int bl = b*6 + l;
  const int rel = mode[b*6]*2 + mode[b*6 + l];
  const float* Abase = x + ((size_t)bl*3136 + (size_t)tile*64)*256;
  const float* Bbase = Wf + (size_t)rel*131072 + nbase;
  const int tid = threadIdx.x;
  const int tx = tid & 15, ty = tid >> 4;
  const int arow = tid >> 2, acol = (tid & 3)*4;
  const int brow = tid >> 4, bcol = (tid & 15)*4;
  float acc[4][4] = {};
  for (int k0 = 0; k0 < 256; k0 += 16) {
    float4 ar = *(const float4*)(Abase + (size_t)arow*256 + k0 + acol);
    float4 br = *(const float4*)(Bbase + (size_t)(k0 + brow)*512 + bcol);
    __syncthreads();
    As[acol+0][arow]=ar.x; As[acol+1][arow]=ar.y; As[acol+2][arow]=ar.z; As[acol+3][arow]=ar.w;
    *(float4*)&Bs[brow][bcol] = br;
    __syncthreads();
    #pragma unroll
    for (int kk = 0; kk < 16; ++kk){
      float4 a4 = *(const float4*)&As[kk][ty*4];
      float4 b4 = *(const float4*)&Bs[kk][tx*4];
      float ar_[4] = {a4.x,a4.y,a4.z,a4.w};
      float br_[4] = {b4.x,b4.y,b4.z,b4.w};
      #pragma unroll
      for (int i = 0; i < 4; ++i)
        #pragma unroll
        for (int j = 0; j < 4; ++j) acc[i][j] += ar_[i]*br_[j];
    }
  }
  const int colBase = nbase + tx*4;
  const bool isK = colBase < 256;
  const int n = colBase & 255;
  const int h = n >> 5, p = n & 31;
  u16* dbuf = isK ? kw : vm;
  float bias[4];
  #pragma unroll
  for (int j = 0; j < 4; ++j) bias[j] = bff[rel*512 + colBase + j];
  #pragma unroll
  for (int i = 0; i < 4; ++i){
    int r = tile*64 + ty*4 + i;           // 0..3135 within (b,l)
    int xy = r / 49, ef = r - xy*49;
    size_t dst = ((((size_t)(bloc*64 + xy)*8 + h)*6 + l)*49 + ef)*32 + p;
    ushort4 pk;
    pk.x = f2bf(acc[i][0] + bias[0]);
    pk.y = f2bf(acc[i][1] + bias[1]);
    pk.z = f2bf(acc[i][2] + bias[2]);
    pk.w = f2bf(acc[i][3] + bias[3]);
    *(ushort4*)(dbuf + dst) = pk;
  }
}

// ---------------------------------------------------------------------------
// K2: q projection (l=0 only). B = Wq[m0] fp32 [e][d] -> transposed tile load.
// ---------------------------------------------------------------------------
__global__ __launch_bounds__(256) void gemm_q(
    const float* __restrict__ x, const int* __restrict__ mode,
    const float* __restrict__ Wq, const float* __restrict__ bq,
    u16* __restrict__ qbuf)
{
  __shared__ float As[16][68];
  __shared__ float Bs[16][68];
  const int nbase = blockIdx.x * 64;      // 0..192
  const int rowT  = blockIdx.y;           // 0..195
  const int b = rowT / 49, tile = rowT % 49;
  const int m0 = mode[b*6];
  const float* Abase = x + ((size_t)b*6*3136 + (size_t)tile*64)*256;
  const float* Wbase = Wq + (size_t)m0*65536;
  const int tid = threadIdx.x;
  const int tx = tid & 15, ty = tid >> 4;
  const int arow = tid >> 2, acol = (tid & 3)*4;
  const int bn = tid >> 2,  bk4 = (tid & 3)*4;
  float acc[4][4] = {};
  for (int k0 = 0; k0 < 256; k0 += 16) {
    float4 ar = *(const float4*)(Abase + (size_t)arow*256 + k0 + acol);
    float4 br = *(const float4*)(Wbase + (size_t)(nbase + bn)*256 + k0 + bk4);
    __syncthreads();
    As[acol+0][arow]=ar.x; As[acol+1][arow]=ar.y; As[acol+2][arow]=ar.z; As[acol+3][arow]=ar.w;
    Bs[bk4+0][bn]=br.x; Bs[bk4+1][bn]=br.y; Bs[bk4+2][bn]=br.z; Bs[bk4+3][bn]=br.w;
    __syncthreads();
    #pragma unroll
    for (int kk = 0; kk < 16; ++kk){
      float4 a4 = *(const float4*)&As[kk][ty*4];
      float4 b4 = *(const float4*)&Bs[kk][tx*4];
      float ar_[4] = {a4.x,a4.y,a4.z,a4.w};
      float br_[4] = {b4.x,b4.y,b4.z,b4.w};
      #pragma unroll
      for (int i = 0; i < 4; ++i)
        #pragma unroll
        for (int j = 0; j < 4; ++j) acc[i][j] += ar_[i]*br_[j];
    }
  }
  const int colBase = nbase + tx*4;
  const int h = colBase >> 5, p = colBase & 31;
  float bias[4];
  #pragma unroll
  for (int j = 0; j < 4; ++j) bias[j] = bq[m0*256 + colBase + j];
  #pragma unroll
  for (int i = 0; i < 4; ++i){
    int r = tile*64 + ty*4 + i;
    int xy = r / 49, ef = r - xy*49;
    size_t dst = (((size_t)(b*64 + xy)*8 + h)*49 + ef)*32 + p;
    ushort4 pk;
    pk.x = f2bf((acc[i][0]+bias[0])*SCALE_Q);
    pk.y = f2bf((acc[i][1]+bias[1])*SCALE_Q);
    pk.z = f2bf((acc[i][2]+bias[2])*SCALE_Q);
    pk.w = f2bf((acc[i][3]+bias[3])*SCALE_Q);
    *(ushort4*)(qbuf + dst) = pk;
  }
}

// ---------------------------------------------------------------------------
// K3: attention, online-softmax over the 6 z-slices.
// One block per (bloc,xy,h) for batches [b0, b0+nb). 49 q x 294 keys.
// LDS = Sz 10192 + qs2 3328 + ks2 3328 + poss 676 + state 588 = 18112 B
//  -> ~8 blocks/CU by LDS, no spill (acc tiles only).
// ---------------------------------------------------------------------------
__global__ __launch_bounds__(256) void attn_kernel(
    const u16* __restrict__ qbuf, const u16* __restrict__ kw,
    const u16* __restrict__ vm,   const float* __restrict__ post,
    u16* __restrict__ aout, int b0)
{
  __shared__ float Sz[49*52];        // per-z scores, then P (exp) in place
  __shared__ u32 qs2[16*52];         // [pp][qi] bf16-pairs, staged once
  __shared__ u32 ks2[16*52];         // K staging [pp][ke]; reused as V flat [ef*16+pp]
  __shared__ float poss[169];
  __shared__ float mS[49], lS[49], aS[49];

  const int bloc  = blockIdx.x >> 9;       // chunk-local batch
  const int local = blockIdx.x & 511;      // xy*8+h
  const int h = local & 7, xy = local >> 3;
  const int bxy = (b0 + bloc)*64 + xy;
  const int tid = threadIdx.x;
  const u32* qsrc = (const u32*)(qbuf + (size_t)(bxy*8 + h)*1568);
  const u16* kwb  = kw + (size_t)blockIdx.x*9408;
  const u16* vmb  = vm + (size_t)blockIdx.x*9408;

  for (int i = tid; i < 784; i += 256) qs2[(i&15)*52 + (i>>4)] = qsrc[i];
  for (int i = tid; i < 169; i += 256) poss[i] = post[i*8 + h];
  if (tid < 49){ mS[tid] = -1e30f; lS[tid] = 0.f; }
  __syncthreads();

  const int qt = tid >> 4, kt = tid & 15;   // 16x16 thread grid (sim phase)
  const int qbase = min(qt*4, 48);          // clamped: keep uint4 loads in-bounds
  const int kbase = min(kt*4, 48);
  // relative-position bias (z-invariant): 4x4 per thread
  float biasv[4][4];
  #pragma unroll
  for (int i = 0; i < 4; ++i){
    int qi = min(qbase + i, 48); int qa = qi/7, qb = qi - qa*7;
    #pragma unroll
    for (int j = 0; j < 4; ++j){
      int ke = min(kbase + j, 48); int ka = ke/7, kb2 = ke - ka*7;
      biasv[i][j] = poss[(qa - ka + 6)*13 + (qb - kb2 + 6)];
    }
  }

  const int pt = tid & 15, qt2 = tid >> 4;  // PV phase mapping (4 qi x 2 p)
  float accx[4] = {0,0,0,0}, accy[4] = {0,0,0,0};

  for (int z = 0; z < 6; ++z){
    __syncthreads();                                   // prev PV done
    { const u32* ksrc = (const u32*)(kwb + (size_t)z*1568);
      for (int i = tid; i < 784; i += 256) ks2[(i&15)*52 + (i>>4)] = ksrc[i]; }
    __syncthreads();

    // ---- Sz = q . k_z + bias ----
    float acc[4][4] = {};
    #pragma unroll
    for (int kkp = 0; kkp < 16; ++kkp){
      uint4 a4 = *(const uint4*)&qs2[kkp*52 + qbase];
      uint4 b4 = *(const uint4*)&ks2[kkp*52 + kbase];
      float ql[4], qh[4], kl[4], kh[4];
      unpack2(a4.x, ql[0], qh[0]); unpack2(a4.y, ql[1], qh[1]);
      unpack2(a4.z, ql[2], qh[2]); unpack2(a4.w, ql[3], qh[3]);
      unpack2(b4.x, kl[0], kh[0]); unpack2(b4.y, kl[1], kh[1]);
      unpack2(b4.z, kl[2], kh[2]); unpack2(b4.w, kl[3], kh[3]);
      #pragma unroll
      for (int i = 0; i < 4; ++i)
        #pragma unroll
        for (int j = 0; j < 4; ++j)
          acc[i][j] += ql[i]*kl[j] + qh[i]*kh[j];
    }
    #pragma unroll
    for (int i = 0; i < 4; ++i){
      int qi = qt*4 + i;
      #pragma unroll
      for (int j = 0; j < 4; ++j){
        int ke = kt*4 + j;
        if (qi < 49 && ke < 49) Sz[qi*52 + ke] = acc[i][j] + biasv[i][j];
      }
    }
    __syncthreads();

    // ---- online-softmax row update (one thread per row) ----
    if (tid < 49){
      float* row = &Sz[tid*52];
      float mold = mS[tid], mx = mold;
      for (int j = 0; j < 49; ++j) mx = fmaxf(mx, row[j]);
      float al = __expf(mold - mx);
      float s = 0.f;
      for (int j = 0; j < 49; ++j){ float e = __expf(row[j]-mx); row[j] = e; s += e; }
      lS[tid] = lS[tid]*al + s;
      mS[tid] = mx;
      aS[tid] = al;
    }
    __syncthreads();

    // ---- stage V_z (overwrites K staging; Sz now holds P) ----
    { const u32* vsrc = (const u32*)(vmb + (size_t)z*1568);
      for (int i = tid; i < 784; i += 256) ks2[i] = vsrc[i]; }   // flat [ef*16+pp]
    __syncthreads();

    // ---- O = O*alpha + P . V_z  (4 qi x 2 p per thread) ----
    float al0 = aS[min(qt2*4 + 0, 48)];
    float al1 = aS[min(qt2*4 + 1, 48)];
    float al2 = aS[min(qt2*4 + 2, 48)];
    float al3 = aS[min(qt2*4 + 3, 48)];
    accx[0]*=al0; accy[0]*=al0; accx[1]*=al1; accy[1]*=al1;
    accx[2]*=al2; accy[2]*=al2; accx[3]*=al3; accy[3]*=al3;
    for (int ef = 0; ef < 49; ++ef){
      float v0, v1; unpack2(ks2[ef*16 + pt], v0, v1);
      #pragma unroll
      for (int i = 0; i < 4; ++i){
        int qi = min(qt2*4 + i, 48);
        float w = Sz[qi*52 + ef];
        accx[i] += w*v0; accy[i] += w*v1;
      }
    }
  }

  // ---- normalize by l and store ----
  u32* outp = (u32*)(aout + (size_t)bxy*12544 + h*32);
  #pragma unroll
  for (int i = 0; i < 4; ++i){
    int qi = qt2*4 + i;
    if (qi < 49){
      float inv = 1.f / lS[qi];
      outp[qi*128 + pt] = pack2(accx[i]*inv, accy[i]*inv);
    }
  }
}

// ---------------------------------------------------------------------------
// K4: final projection. A = attn out (bf16), B = Wa[m0] fp32 [e][d], bias ba.
// Output fp32 to d_out.
// ---------------------------------------------------------------------------
__global__ __launch_bounds__(256) void gemm_out(
    const u16* __restrict__ aout, const int* __restrict__ mode,
    const float* __restrict__ Wa, const float* __restrict__ ba,
    float* __restrict__ outp)
{
  __shared__ float As[16][68];
  __shared__ float Bs[16][68];
  const int nbase = blockIdx.x * 64;
  const int rowT  = blockIdx.y;           // 0..195
  const int b = rowT / 49, tile = rowT % 49;
  const int m0 = mode[b*6];
  const u16* Abase = aout + ((size_t)b*3136 + (size_t)tile*64)*256;
  const float* Wbase = Wa + (size_t)m0*65536;
  const int tid = threadIdx.x;
  const int tx = tid & 15, ty = tid >> 4;
  const int arow = tid >> 2, acol = (tid & 3)*4;
  const int bn = tid >> 2,  bk4 = (tid & 3)*4;
  float acc[4][4] = {};
  for (int k0 = 0; k0 < 256; k0 += 16) {
    uint2  ar = *(const uint2*)(Abase + (size_t)arow*256 + k0 + acol);
    float4 br = *(const float4*)(Wbase + (size_t)(nbase + bn)*256 + k0 + bk4);
    __syncthreads();
    { float a0,a1,a2,a3; unpack2(ar.x,a0,a1); unpack2(ar.y,a2,a3);
      As[acol+0][arow]=a0; As[acol+1][arow]=a1; As[acol+2][arow]=a2; As[acol+3][arow]=a3; }
    Bs[bk4+0][bn]=br.x; Bs[bk4+1][bn]=br.y; Bs[bk4+2][bn]=br.z; Bs[bk4+3][bn]=br.w;
    __syncthreads();
    #pragma unroll
    for (int kk = 0; kk < 16; ++kk){
      float4 a4 = *(const float4*)&As[kk][ty*4];
      float4 b4 = *(const float4*)&Bs[kk][tx*4];
      float ar_[4] = {a4.x,a4.y,a4.z,a4.w};
      float br_[4] = {b4.x,b4.y,b4.z,b4.w};
      #pragma unroll
      for (int i = 0; i < 4; ++i)
        #pragma unroll
        for (int j = 0; j < 4; ++j) acc[i][j] += ar_[i]*br_[j];
    }
  }
  const int colBase = nbase + tx*4;
  float bias[4];
  #pragma unroll
  for (int j = 0; j < 4; ++j) bias[j] = ba[m0*256 + colBase + j];
  #pragma unroll
  for (int i = 0; i < 4; ++i){
    int rowg = b*3136 + tile*64 + ty*4 + i;
    float4 o;
    o.x = acc[i][0] + bias[0];
    o.y = acc[i][1] + bias[1];
    o.z = acc[i][2] + bias[2];
    o.w = acc[i][3] + bias[3];
    *(float4*)(outp + (size_t)rowg*256 + colBase) = o;
  }
}

// ---------------------------------------------------------------------------
extern "C" void kernel_launch(void* const* d_in, const int* in_sizes, int n_in,
                              void* d_out, int out_size, void* d_ws, size_t ws_size,
                              hipStream_t stream)
{
  float* outp = (float*)d_out;
  const int FLAG_GRID = (out_size + 255)/256;

  // ---- runtime diagnostics (constant across calls -> graph-safe) ----
  if (n_in != 13) { flag_fill<<<FLAG_GRID,256,0,stream>>>(outp, out_size, 2000.f); return; }
  if (in_sizes[0] != 4*6*64*49*256) { flag_fill<<<FLAG_GRID,256,0,stream>>>(outp, out_size, 3000.f); return; }
  if (in_sizes[1] != 24) { flag_fill<<<FLAG_GRID,256,0,stream>>>(outp, out_size, 4000.f); return; }

  const size_t SZ_WF   = (size_t)4*256*512*sizeof(float);   //  2 MB
  const size_t SZ_BFF  = (size_t)4*512*sizeof(float);       //  8 KB
  const size_t SZ_Q    = (size_t)12544*256*2;               //  6.4 MB
  const size_t SZ_KW1  = (size_t)64*8*6*49*32*2;            //  9.63 MB per batch
  const size_t SZ_AOUT = (size_t)12544*256*2;               //  6.4 MB
  const size_t FIXED   = SZ_WF + SZ_BFF + SZ_Q + SZ_AOUT;
  if (ws_size < FIXED + 2*SZ_KW1) { flag_fill<<<FLAG_GRID,256,0,stream>>>(outp, out_size, 1000.f); return; }

  // adaptive chunking: as many batches per kw/vm buffer as the workspace allows
  int nb = 1;
  if (ws_size >= FIXED + 8*SZ_KW1) nb = 4;
  else if (ws_size >= FIXED + 4*SZ_KW1) nb = 2;

  const float* x    = (const float*)d_in[0];
  const int*   mode = (const int*)d_in[1];
  const float* Wq   = (const float*)d_in[2];
  const float* bq   = (const float*)d_in[3];
  const float* Wk   = (const float*)d_in[4];
  const float* bk   = (const float*)d_in[5];
  const float* Wv   = (const float*)d_in[6];
  const float* bv   = (const float*)d_in[7];
  const float* Wa   = (const float*)d_in[8];
  const float* ba   = (const float*)d_in[9];
  const float* Ratt = (const float*)d_in[10];
  const float* Rmsg = (const float*)d_in[11];
  const float* post = (const float*)d_in[12];

  char* w = (char*)d_ws;
  float* Wf   = (float*)w;  w += SZ_WF;
  float* bff  = (float*)w;  w += SZ_BFF;
  u16* qbuf   = (u16*)w;    w += SZ_Q;
  u16* aout   = (u16*)w;    w += SZ_AOUT;
  u16* kwbuf  = (u16*)w;    w += (size_t)nb*SZ_KW1;
  u16* vmbuf  = (u16*)w;    w += (size_t)nb*SZ_KW1;

  fuse_w<<<dim3(4,256), 512, 0, stream>>>(Wk, Wv, Ratt, Rmsg, Wf);
  fuse_b<<<4, 512, 0, stream>>>(bk, bv, Ratt, Rmsg, bff);
  gemm_q<<<dim3(4,196), 256, 0, stream>>>(x, mode, Wq, bq, qbuf);
  for (int b0 = 0; b0 < 4; b0 += nb) {
    gemm_kwv<<<dim3(8, nb*294), 256, 0, stream>>>(x, mode, Wf, bff, kwbuf, vmbuf, b0);
    attn_kernel<<<nb*512, 256, 0, stream>>>(qbuf, kwbuf, vmbuf, post, aout, b0);
  }
  gemm_out<<<dim3(4,196), 256, 0, stream>>>(aout, mode, Wa, ba, outp);
}

// Round 5
// 416.148 us; speedup vs baseline: 3.7370x; 1.8286x over previous
//
#include <hip/hip_runtime.h>

typedef unsigned short u16;
typedef unsigned int   u32;
typedef _Float16 f16;
typedef _Float16 h2  __attribute__((ext_vector_type(2)));
typedef _Float16 h8  __attribute__((ext_vector_type(8)));
typedef float    fx4 __attribute__((ext_vector_type(4)));

// ---- problem constants ----
// B=4 L=6 X=Y=8 -> 256 sites, W=49 window, D=256, h=8, dh=32
#define SCALE_Q 0.17677669529663687f

__device__ __forceinline__ u16 f2h_bits(float f){
  union{ f16 h; u16 u; } v; v.h = (f16)f; return v.u;
}
__device__ __forceinline__ u32 packh2(float a, float b){
  union{ h2 h; u32 u; } v; v.h = h2{(f16)a, (f16)b}; return v.u;
}
__device__ __forceinline__ h2 as_h2(u32 x){
  union{ u32 u; h2 h; } v; v.u = x; return v.h;
}

// diagnostic fill (fp32): encodes which runtime assumption failed
__global__ void flag_fill(float* out, int n, float v){
  int i = blockIdx.x*256 + threadIdx.x;
  if (i < n) out[i] = v;
}

// ---------------------------------------------------------------------------
// K0: fuse relation matrices into projection weights (fp32 in, f16 out,
// TRANSPOSED for MFMA B-staging): Wft[rel][n][d].
// ---------------------------------------------------------------------------
__global__ __launch_bounds__(512) void fuse_w(
    const float* __restrict__ Wk, const float* __restrict__ Wv,
    const float* __restrict__ Ratt, const float* __restrict__ Rmsg,
    u16* __restrict__ Wft)
{
  const int rel = blockIdx.x;      // 0..3
  const int d   = blockIdx.y;      // 0..255
  const int n   = threadIdx.x;     // 0..511
  const int ml  = rel & 1;
  float acc = 0.f;
  if (n < 256) {
    const int h = n >> 5, p = n & 31;
    const float* wcol = Wk + (size_t)ml*65536 + (size_t)(h*32)*256 + d;
    const float* rrow = Ratt + ((size_t)(rel*8 + h)*32 + p)*32;
    #pragma unroll
    for (int q = 0; q < 32; ++q) acc += wcol[q*256] * rrow[q];
  } else {
    const int n2 = n - 256, h = n2 >> 5, qq = n2 & 31;
    const float* wcol = Wv + (size_t)ml*65536 + (size_t)(h*32)*256 + d;
    const float* rcol = Rmsg + ((size_t)(rel*8 + h)*32)*32 + qq;
    #pragma unroll
    for (int p2 = 0; p2 < 32; ++p2) acc += wcol[p2*256] * rcol[p2*32];
  }
  Wft[((size_t)rel*512 + n)*256 + d] = f2h_bits(acc);
}

__global__ __launch_bounds__(512) void fuse_b(
    const float* __restrict__ bk, const float* __restrict__ bv,
    const float* __restrict__ Ratt, const float* __restrict__ Rmsg,
    float* __restrict__ bff)
{
  const int rel = blockIdx.x, n = threadIdx.x, ml = rel & 1;
  float acc = 0.f;
  if (n < 256) {
    const int h = n >> 5, p = n & 31;
    const float* rrow = Ratt + ((size_t)(rel*8 + h)*32 + p)*32;
    #pragma unroll
    for (int q = 0; q < 32; ++q) acc += bk[ml*256 + h*32 + q] * rrow[q];
  } else {
    const int n2 = n - 256, h = n2 >> 5, qq = n2 & 31;
    const float* rcol = Rmsg + ((size_t)(rel*8 + h)*32)*32 + qq;
    #pragma unroll
    for (int p2 = 0; p2 < 32; ++p2) acc += bv[ml*256 + h*32 + p2] * rcol[p2*32];
  }
  bff[rel*512 + n] = acc;
}

// ---------------------------------------------------------------------------
// K1: fused kw / v_msg projection GEMM — MFMA (16x16x32 f16).
// BM=64, BN=64, BK=32; 256 thr = 4 waves, wave w owns rows [w*16, w*16+16).
// Outputs (f16):
//   kw[bloc][xy][h][l][ef][p]   (p-contiguous for QK pair loads)
//   vm[bloc][xy][h][l][p][50]   (ef-contiguous+pad for PV dot2 loads)
// ---------------------------------------------------------------------------
__global__ __launch_bounds__(256) void gemm_kwv(
    const float* __restrict__ x, const int* __restrict__ mode,
    const u16* __restrict__ Wft, const float* __restrict__ bff,
    u16* __restrict__ kw, u16* __restrict__ vm, int b0)
{
  __shared__ u16 As[64*32];   // [m][k]
  __shared__ u16 Bs[64*32];   // [n][k]
  const int nbase = blockIdx.x * 64;         // 0..448
  const int rowT  = blockIdx.y;              // bloc*294 + l*49 + tile
  const int bloc = rowT / 294;
  const int rem  = rowT % 294;
  const int l = rem / 49, tile = rem % 49;
  const int b = b0 + bloc;
  const int rel = mode[b*6]*2 + mode[b*6 + l];
  const float* Abase = x + ((size_t)(b*6 + l)*3136 + (size_t)tile*64)*256;
  const u16*   Bbase = Wft + (size_t)rel*131072 + (size_t)nbase*256;
  const int tid  = threadIdx.x;
  const int wave = tid >> 6, lane = tid & 63;
  const int quad = lane >> 4, l15 = lane & 15;
  const int srow = tid >> 2, sseg = (tid & 3)*8;   // staging: 4 threads/row

  fx4 acc[4] = {fx4{0,0,0,0}, fx4{0,0,0,0}, fx4{0,0,0,0}, fx4{0,0,0,0}};

  for (int k0 = 0; k0 < 256; k0 += 32) {
    float4 a0 = *(const float4*)(Abase + (size_t)srow*256 + k0 + sseg);
    float4 a1 = *(const float4*)(Abase + (size_t)srow*256 + k0 + sseg + 4);
    uint4  bw = *(const uint4*)(Bbase + (size_t)srow*256 + k0 + sseg);
    __syncthreads();   // prior frag reads done
    uint4 ap;
    ap.x = packh2(a0.x, a0.y); ap.y = packh2(a0.z, a0.w);
    ap.z = packh2(a1.x, a1.y); ap.w = packh2(a1.z, a1.w);
    *(uint4*)&As[srow*32 + sseg] = ap;
    *(uint4*)&Bs[srow*32 + sseg] = bw;
    __syncthreads();
    h8 af = *(const h8*)&As[(wave*16 + l15)*32 + quad*8];
    #pragma unroll
    for (int j = 0; j < 4; ++j){
      h8 bf = *(const h8*)&Bs[(j*16 + l15)*32 + quad*8];
      acc[j] = __builtin_amdgcn_mfma_f32_16x16x32_f16(af, bf, acc[j], 0, 0, 0);
    }
  }

  // epilogue: D row = quad*4+reg (within wave's 16 rows), col = l15
  #pragma unroll
  for (int j = 0; j < 4; ++j){
    const int n = nbase + j*16 + l15;
    const float bias = bff[rel*512 + n];
    #pragma unroll
    for (int reg = 0; reg < 4; ++reg){
      const int r = tile*64 + wave*16 + quad*4 + reg;   // 0..3135
      const int xy = r / 49, ef = r - xy*49;
      const float val = acc[j][reg] + bias;
      if (n < 256){
        const int hh = n >> 5, p = n & 31;
        kw[((((size_t)(bloc*64 + xy)*8 + hh)*6 + l)*49 + ef)*32 + p] = f2h_bits(val);
      } else {
        const int n2 = n - 256, hh = n2 >> 5, p = n2 & 31;
        vm[((((size_t)(bloc*64 + xy)*8 + hh)*6 + l)*32 + p)*50 + ef] = f2h_bits(val);
      }
    }
  }
}

// ---------------------------------------------------------------------------
// K2: q projection (l=0 only), VALU 4x4, f16 output.
// ---------------------------------------------------------------------------
__global__ __launch_bounds__(256) void gemm_q(
    const float* __restrict__ x, const int* __restrict__ mode,
    const float* __restrict__ Wq, const float* __restrict__ bq,
    u16* __restrict__ qbuf)
{
  __shared__ float As[16][68];
  __shared__ float Bs[16][68];
  const int nbase = blockIdx.x * 64;      // 0..192
  const int rowT  = blockIdx.y;           // 0..195
  const int b = rowT / 49, tile = rowT % 49;
  const int m0 = mode[b*6];
  const float* Abase = x + ((size_t)b*6*3136 + (size_t)tile*64)*256;
  const float* Wbase = Wq + (size_t)m0*65536;
  const int tid = threadIdx.x;
  const int tx = tid & 15, ty = tid >> 4;
  const int arow = tid >> 2, acol = (tid & 3)*4;
  const int bn = tid >> 2,  bk4 = (tid & 3)*4;
  float acc[4][4] = {};
  for (int k0 = 0; k0 < 256; k0 += 16) {
    float4 ar = *(const float4*)(Abase + (size_t)arow*256 + k0 + acol);
    float4 br = *(const float4*)(Wbase + (size_t)(nbase + bn)*256 + k0 + bk4);
    __syncthreads();
    As[acol+0][arow]=ar.x; As[acol+1][arow]=ar.y; As[acol+2][arow]=ar.z; As[acol+3][arow]=ar.w;
    Bs[bk4+0][bn]=br.x; Bs[bk4+1][bn]=br.y; Bs[bk4+2][bn]=br.z; Bs[bk4+3][bn]=br.w;
    __syncthreads();
    #pragma unroll
    for (int kk = 0; kk < 16; ++kk){
      float4 a4 = *(const float4*)&As[kk][ty*4];
      float4 b4 = *(const float4*)&Bs[kk][tx*4];
      float ar_[4] = {a4.x,a4.y,a4.z,a4.w};
      float br_[4] = {b4.x,b4.y,b4.z,b4.w};
      #pragma unroll
      for (int i = 0; i < 4; ++i)
        #pragma unroll
        for (int j = 0; j < 4; ++j) acc[i][j] += ar_[i]*br_[j];
    }
  }
  const int colBase = nbase + tx*4;
  const int h = colBase >> 5, p = colBase & 31;
  float bias[4];
  #pragma unroll
  for (int j = 0; j < 4; ++j) bias[j] = bq[m0*256 + colBase + j];
  #pragma unroll
  for (int i = 0; i < 4; ++i){
    int r = tile*64 + ty*4 + i;
    int xy = r / 49, ef = r - xy*49;
    size_t dst = (((size_t)(b*64 + xy)*8 + h)*49 + ef)*32 + p;
    ushort4 pk;
    pk.x = f2h_bits((acc[i][0]+bias[0])*SCALE_Q);
    pk.y = f2h_bits((acc[i][1]+bias[1])*SCALE_Q);
    pk.z = f2h_bits((acc[i][2]+bias[2])*SCALE_Q);
    pk.w = f2h_bits((acc[i][3]+bias[3])*SCALE_Q);
    *(ushort4*)(qbuf + dst) = pk;
  }
}

// ---------------------------------------------------------------------------
// K3: attention — ONE WAVE per (bloc,xy,h); lane = query row qi (49 active).
// Scores S[49], online-softmax state, O[32] all in REGISTERS.
// K_z / V^T_z staged in LDS, read via broadcast b128 (conflict-free).
// QK^T and PV via v_dot2_f32_f16. LDS = 10192+3136+3584+676 = 17.6 KB.
// ---------------------------------------------------------------------------
__global__ __launch_bounds__(64) void attn_kernel(
    const u16* __restrict__ qbuf, const u16* __restrict__ kw,
    const u16* __restrict__ vm,   const float* __restrict__ post,
    u16* __restrict__ aout, int b0)
{
  __shared__ float biasT[49*52];   // [ke][qi] — lane-linear reads
  __shared__ u32 Ks[784];          // K_z  flat [ef*16 + pp]
  __shared__ u32 VTs[32*28];       // V^T_z [p][28] (25 used, 3 pad)
  __shared__ float poss[169];

  const int bloc  = blockIdx.x >> 9;
  const int local = blockIdx.x & 511;      // xy*8+h
  const int h = local & 7, xy = local >> 3;
  const int bxy = (b0 + bloc)*64 + xy;
  const int tid = threadIdx.x;             // 0..63
  const int qi = min(tid, 48);             // lane's query row (clamped)

  for (int i = tid; i < 169; i += 64) poss[i] = post[i*8 + h];
  __syncthreads();

  if (tid < 49){
    const int qa = qi/7, qb = qi - qa*7;
    for (int ka = 0; ka < 7; ++ka)
      for (int kb = 0; kb < 7; ++kb)
        biasT[(ka*7+kb)*52 + qi] = poss[(qa - ka + 6)*13 + (qb - kb + 6)];
  }

  // Q row into registers (16 u32 = 32 f16)
  u32 Qw[16];
  { const uint4* qsrc = (const uint4*)(qbuf + (size_t)(bxy*8 + h)*1568 + (size_t)qi*32);
    uint4 t0 = qsrc[0], t1 = qsrc[1], t2 = qsrc[2], t3 = qsrc[3];
    Qw[0]=t0.x; Qw[1]=t0.y; Qw[2]=t0.z; Qw[3]=t0.w;
    Qw[4]=t1.x; Qw[5]=t1.y; Qw[6]=t1.z; Qw[7]=t1.w;
    Qw[8]=t2.x; Qw[9]=t2.y; Qw[10]=t2.z; Qw[11]=t2.w;
    Qw[12]=t3.x; Qw[13]=t3.y; Qw[14]=t3.z; Qw[15]=t3.w; }

  const size_t kvbase = ((size_t)(bloc*64 + xy)*8 + h)*6;
  float mprev = -1e30f, lsum = 0.f;
  float O[32];
  #pragma unroll
  for (int p = 0; p < 32; ++p) O[p] = 0.f;

  for (int z = 0; z < 6; ++z){
    __syncthreads();   // prior phase's LDS reads complete (also covers biasT build)
    { const u32* ksrc = (const u32*)(kw) + (kvbase + z)*49*16;
      for (int i = tid; i < 784; i += 64) Ks[i] = ksrc[i];
      const u32* vsrc = (const u32*)(vm) + (kvbase + z)*32*25;
      for (int i = tid; i < 800; i += 64){
        int p = i / 25, rm = i - p*25;
        VTs[p*28 + rm] = vsrc[i];
      } }
    __syncthreads();

    // ---- S[ke] = q . k_z + bias ----
    float S[49];
    #pragma unroll
    for (int ke = 0; ke < 49; ++ke){
      float s = biasT[ke*52 + qi];
      #pragma unroll
      for (int q4 = 0; q4 < 4; ++q4){
        uint4 k4 = *(const uint4*)&Ks[ke*16 + q4*4];
        s = __builtin_amdgcn_fdot2(as_h2(Qw[q4*4+0]), as_h2(k4.x), s, false);
        s = __builtin_amdgcn_fdot2(as_h2(Qw[q4*4+1]), as_h2(k4.y), s, false);
        s = __builtin_amdgcn_fdot2(as_h2(Qw[q4*4+2]), as_h2(k4.z), s, false);
        s = __builtin_amdgcn_fdot2(as_h2(Qw[q4*4+3]), as_h2(k4.w), s, false);
      }
      S[ke] = s;
    }

    // ---- online softmax (lane-local) ----
    float mx = mprev;
    #pragma unroll
    for (int ke = 0; ke < 49; ++ke) mx = fmaxf(mx, S[ke]);
    const float alpha = __expf(mprev - mx);
    float sum = 0.f;
    #pragma unroll
    for (int ke = 0; ke < 49; ++ke){ float e = __expf(S[ke]-mx); S[ke] = e; sum += e; }
    lsum = lsum*alpha + sum;
    mprev = mx;
    #pragma unroll
    for (int p = 0; p < 32; ++p) O[p] *= alpha;

    // ---- pack P to f16 pairs ----
    u32 Pp[25];
    #pragma unroll
    for (int kp = 0; kp < 24; ++kp) Pp[kp] = packh2(S[2*kp], S[2*kp+1]);
    Pp[24] = packh2(S[48], 0.f);

    // ---- O += P . V_z ----
    #pragma unroll
    for (int p = 0; p < 32; ++p){
      float o = O[p];
      #pragma unroll
      for (int c = 0; c < 6; ++c){
        uint4 v4 = *(const uint4*)&VTs[p*28 + c*4];
        o = __builtin_amdgcn_fdot2(as_h2(Pp[c*4+0]), as_h2(v4.x), o, false);
        o = __builtin_amdgcn_fdot2(as_h2(Pp[c*4+1]), as_h2(v4.y), o, false);
        o = __builtin_amdgcn_fdot2(as_h2(Pp[c*4+2]), as_h2(v4.z), o, false);
        o = __builtin_amdgcn_fdot2(as_h2(Pp[c*4+3]), as_h2(v4.w), o, false);
      }
      o = __builtin_amdgcn_fdot2(as_h2(Pp[24]), as_h2(VTs[p*28 + 24]), o, false);
      O[p] = o;
    }
  }

  // ---- normalize + store (f16) ----
  if (tid < 49){
    const float inv = 1.f / lsum;
    u32* outw = (u32*)(aout + (size_t)bxy*12544 + h*32);
    #pragma unroll
    for (int pp = 0; pp < 16; ++pp)
      outw[(size_t)qi*128 + pp] = packh2(O[2*pp]*inv, O[2*pp+1]*inv);
  }
}

// ---------------------------------------------------------------------------
// K4: final projection. A = attn out (f16), B = Wa[m0] fp32 [e][d], bias ba.
// ---------------------------------------------------------------------------
__global__ __launch_bounds__(256) void gemm_out(
    const u16* __restrict__ aout, const int* __restrict__ mode,
    const float* __restrict__ Wa, const float* __restrict__ ba,
    float* __restrict__ outp)
{
  __shared__ float As[16][68];
  __shared__ float Bs[16][68];
  const int nbase = blockIdx.x * 64;
  const int rowT  = blockIdx.y;           // 0..195
  const int b = rowT / 49, tile = rowT % 49;
  const int m0 = mode[b*6];
  const u16* Abase = aout + ((size_t)b*3136 + (size_t)tile*64)*256;
  const float* Wbase = Wa + (size_t)m0*65536;
  const int tid = threadIdx.x;
  const int tx = tid & 15, ty = tid >> 4;
  const int arow = tid >> 2, acol = (tid & 3)*4;
  const int bn = tid >> 2,  bk4 = (tid & 3)*4;
  float acc[4][4] = {};
  for (int k0 = 0; k0 < 256; k0 += 16) {
    uint2  ar = *(const uint2*)(Abase + (size_t)arow*256 + k0 + acol);
    float4 br = *(const float4*)(Wbase + (size_t)(nbase + bn)*256 + k0 + bk4);
    __syncthreads();
    { h2 lo = as_h2(ar.x), hi = as_h2(ar.y);
      As[acol+0][arow]=(float)lo.x; As[acol+1][arow]=(float)lo.y;
      As[acol+2][arow]=(float)hi.x; As[acol+3][arow]=(float)hi.y; }
    Bs[bk4+0][bn]=br.x; Bs[bk4+1][bn]=br.y; Bs[bk4+2][bn]=br.z; Bs[bk4+3][bn]=br.w;
    __syncthreads();
    #pragma unroll
    for (int kk = 0; kk < 16; ++kk){
      float4 a4 = *(const float4*)&As[kk][ty*4];
      float4 b4 = *(const float4*)&Bs[kk][tx*4];
      float ar_[4] = {a4.x,a4.y,a4.z,a4.w};
      float br_[4] = {b4.x,b4.y,b4.z,b4.w};
      #pragma unroll
      for (int i = 0; i < 4; ++i)
        #pragma unroll
        for (int j = 0; j < 4; ++j) acc[i][j] += ar_[i]*br_[j];
    }
  }
  const int colBase = nbase + tx*4;
  float bias[4];
  #pragma unroll
  for (int j = 0; j < 4; ++j) bias[j] = ba[m0*256 + colBase + j];
  #pragma unroll
  for (int i = 0; i < 4; ++i){
    int rowg = b*3136 + tile*64 + ty*4 + i;
    float4 o;
    o.x = acc[i][0] + bias[0];
    o.y = acc[i][1] + bias[1];
    o.z = acc[i][2] + bias[2];
    o.w = acc[i][3] + bias[3];
    *(float4*)(outp + (size_t)rowg*256 + colBase) = o;
  }
}

// ---------------------------------------------------------------------------
extern "C" void kernel_launch(void* const* d_in, const int* in_sizes, int n_in,
                              void* d_out, int out_size, void* d_ws, size_t ws_size,
                              hipStream_t stream)
{
  float* outp = (float*)d_out;
  const int FLAG_GRID = (out_size + 255)/256;

  if (n_in != 13) { flag_fill<<<FLAG_GRID,256,0,stream>>>(outp, out_size, 2000.f); return; }
  if (in_sizes[0] != 4*6*64*49*256) { flag_fill<<<FLAG_GRID,256,0,stream>>>(outp, out_size, 3000.f); return; }
  if (in_sizes[1] != 24) { flag_fill<<<FLAG_GRID,256,0,stream>>>(outp, out_size, 4000.f); return; }

  const size_t SZ_WFT  = (size_t)4*512*256*2;               //  1 MB (f16)
  const size_t SZ_BFF  = (size_t)4*512*sizeof(float);       //  8 KB
  const size_t SZ_Q    = (size_t)12544*256*2;               //  6.4 MB (f16)
  const size_t SZ_AOUT = (size_t)12544*256*2;               //  6.4 MB (f16)
  const size_t SZ_KW1  = (size_t)64*8*6*49*32*2;            //  9.63 MB / batch
  const size_t SZ_VM1  = (size_t)64*8*6*32*50*2;            //  9.83 MB / batch
  const size_t FIXED   = SZ_WFT + SZ_BFF + SZ_Q + SZ_AOUT;
  if (ws_size < FIXED + SZ_KW1 + SZ_VM1) { flag_fill<<<FLAG_GRID,256,0,stream>>>(outp, out_size, 1000.f); return; }

  int nb = 1;
  if (ws_size >= FIXED + 4*(SZ_KW1 + SZ_VM1)) nb = 4;
  else if (ws_size >= FIXED + 2*(SZ_KW1 + SZ_VM1)) nb = 2;

  const float* x    = (const float*)d_in[0];
  const int*   mode = (const int*)d_in[1];
  const float* Wq   = (const float*)d_in[2];
  const float* bq   = (const float*)d_in[3];
  const float* Wk   = (const float*)d_in[4];
  const float* bk   = (const float*)d_in[5];
  const float* Wv   = (const float*)d_in[6];
  const float* bv   = (const float*)d_in[7];
  const float* Wa   = (const float*)d_in[8];
  const float* ba   = (const float*)d_in[9];
  const float* Ratt = (const float*)d_in[10];
  const float* Rmsg = (const float*)d_in[11];
  const float* post = (const float*)d_in[12];

  char* w = (char*)d_ws;
  u16* Wft   = (u16*)w;   w += SZ_WFT;
  float* bff = (float*)w; w += SZ_BFF;
  u16* qbuf  = (u16*)w;   w += SZ_Q;
  u16* aout  = (u16*)w;   w += SZ_AOUT;
  u16* kwbuf = (u16*)w;   w += (size_t)nb*SZ_KW1;
  u16* vmbuf = (u16*)w;   w += (size_t)nb*SZ_VM1;

  fuse_w<<<dim3(4,256), 512, 0, stream>>>(Wk, Wv, Ratt, Rmsg, Wft);
  fuse_b<<<4, 512, 0, stream>>>(bk, bv, Ratt, Rmsg, bff);
  gemm_q<<<dim3(4,196), 256, 0, stream>>>(x, mode, Wq, bq, qbuf);
  for (int b0 = 0; b0 < 4; b0 += nb) {
    gemm_kwv<<<dim3(8, nb*294), 256, 0, stream>>>(x, mode, Wft, bff, kwbuf, vmbuf, b0);
    attn_kernel<<<nb*512, 64, 0, stream>>>(qbuf, kwbuf, vmbuf, post, aout, b0);
  }
  gemm_out<<<dim3(4,196), 256, 0, stream>>>(aout, mode, Wa, ba, outp);
}